// Round 1
// baseline (593.614 us; speedup 1.0000x reference)
//
#include <hip/hip_runtime.h>

#define N_PTS 8192
#define BATCH 2
#define KNN 8
#define STILE 2048   // smoothness LDS tile (points)

// ---------------- init: min arrays to +inf bits, out to 0 ----------------
__global__ void init_kernel(unsigned int* __restrict__ mins, float* __restrict__ out, int n) {
    int i = blockIdx.x * blockDim.x + threadIdx.x;
    if (i < n) mins[i] = 0x7F800000u;  // +inf
    if (i == 0) out[0] = 0.0f;
}

// ---------------- chamfer directional min ----------------
// dir==0: rows = pc1+flow, cols = pc2   (d1)
// dir==1: rows = pc2,      cols = pc1+flow (d2)
__global__ void chamfer_min_kernel(const float* __restrict__ pc1,
                                   const float* __restrict__ pc2,
                                   const float* __restrict__ flow,
                                   unsigned int* __restrict__ mins,
                                   int dir) {
    const int b = blockIdx.z;
    const int i = blockIdx.x * 256 + threadIdx.x;
    const float* base1 = pc1 + (size_t)b * N_PTS * 3;
    const float* base2 = pc2 + (size_t)b * N_PTS * 3;
    const float* fl    = flow + (size_t)b * N_PTS * 3;

    float px, py, pz;
    if (dir == 0) {
        px = base1[i*3+0] + fl[i*3+0];
        py = base1[i*3+1] + fl[i*3+1];
        pz = base1[i*3+2] + fl[i*3+2];
    } else {
        px = base2[i*3+0];
        py = base2[i*3+1];
        pz = base2[i*3+2];
    }

    const int sliceLen = N_PTS / gridDim.y;
    const int m0 = blockIdx.y * sliceLen;

    __shared__ float sm[256 * 3];
    float best = __builtin_inff();

    for (int t = 0; t < sliceLen; t += 256) {
        int j = m0 + t + threadIdx.x;
        float ox, oy, oz;
        if (dir == 0) {
            ox = base2[j*3+0]; oy = base2[j*3+1]; oz = base2[j*3+2];
        } else {
            ox = base1[j*3+0] + fl[j*3+0];
            oy = base1[j*3+1] + fl[j*3+1];
            oz = base1[j*3+2] + fl[j*3+2];
        }
        __syncthreads();
        sm[threadIdx.x*3+0] = ox;
        sm[threadIdx.x*3+1] = oy;
        sm[threadIdx.x*3+2] = oz;
        __syncthreads();
        #pragma unroll 8
        for (int jj = 0; jj < 256; ++jj) {
            float dx = px - sm[jj*3+0];
            float dy = py - sm[jj*3+1];
            float dz = pz - sm[jj*3+2];
            float d = fmaf(dx, dx, fmaf(dy, dy, dz*dz));
            best = fminf(best, d);
        }
    }
    atomicMin(&mins[(size_t)b * N_PTS + i], __float_as_uint(best));
}

// ---------------- chamfer reduce: sum sqrt(min)/ (B*N) ----------------
__global__ void chamfer_reduce_kernel(const unsigned int* __restrict__ mins,
                                      float* __restrict__ out) {
    int i = blockIdx.x * 256 + threadIdx.x;  // 128 blocks * 256 = 32768 entries
    float v = sqrtf(__uint_as_float(mins[i])) * (1.0f / (float)(BATCH * N_PTS));
    #pragma unroll
    for (int off = 32; off > 0; off >>= 1) v += __shfl_down(v, off, 64);
    __shared__ float wsum[4];
    int wid = threadIdx.x >> 6;
    if ((threadIdx.x & 63) == 0) wsum[wid] = v;
    __syncthreads();
    if (threadIdx.x == 0) {
        atomicAdd(out, wsum[0] + wsum[1] + wsum[2] + wsum[3]);
    }
}

// ---------------- smoothness: kNN-8 + flow-diff norms ----------------
// 256 threads: 32 points/block, 8 sub-threads/point (interleaved j scan).
__global__ void smooth_kernel(const float* __restrict__ pc1,
                              const float* __restrict__ flow,
                              float* __restrict__ out) {
    const int b = blockIdx.y;
    const int p_local = threadIdx.x >> 3;  // 0..31
    const int sub     = threadIdx.x & 7;   // 0..7
    const int i = blockIdx.x * 32 + p_local;
    const float* P = pc1  + (size_t)b * N_PTS * 3;
    const float* F = flow + (size_t)b * N_PTS * 3;

    float px = P[i*3+0], py = P[i*3+1], pz = P[i*3+2];

    float bd[KNN];
    int   bi[KNN];
    #pragma unroll
    for (int k = 0; k < KNN; ++k) { bd[k] = __builtin_inff(); bi[k] = 0; }

    __shared__ float sj[STILE * 3];  // 24 KiB; reused for merge below

    for (int t0 = 0; t0 < N_PTS; t0 += STILE) {
        __syncthreads();
        // coalesced float4 staging: STILE*3 floats = STILE*3/4 float4
        const float4* src = (const float4*)(P + (size_t)t0 * 3);
        float4* dst = (float4*)sj;
        for (int u = threadIdx.x; u < STILE * 3 / 4; u += 256) dst[u] = src[u];
        __syncthreads();
        for (int jj = sub; jj < STILE; jj += 8) {
            int j = t0 + jj;
            float dx = px - sj[jj*3+0];
            float dy = py - sj[jj*3+1];
            float dz = pz - sj[jj*3+2];
            float d = fmaf(dx, dx, fmaf(dy, dy, dz*dz));
            if (d < bd[KNN-1] && j != i) {
                float cd = d; int ci = j;
                #pragma unroll
                for (int k = 0; k < KNN; ++k) {
                    if (cd < bd[k]) {
                        float td = bd[k]; bd[k] = cd; cd = td;
                        int   ti = bi[k]; bi[k] = ci; ci = ti;
                    }
                }
            }
        }
    }

    // merge the 8 sub-threads' top-8 lists per point
    __syncthreads();
    float* cdm = sj;                 // [32][64] dists
    int*   cim = (int*)(sj + 2048);  // [32][64] indices
    #pragma unroll
    for (int k = 0; k < KNN; ++k) {
        cdm[p_local*64 + sub*8 + k] = bd[k];
        cim[p_local*64 + sub*8 + k] = bi[k];
    }
    __syncthreads();

    __shared__ float psum[32];
    if (sub == 0) {
        for (int c = 8; c < 64; ++c) {  // own 8 already resident in bd/bi
            float d = cdm[p_local*64 + c];
            if (d < bd[KNN-1]) {
                float cd = d; int ci = cim[p_local*64 + c];
                #pragma unroll
                for (int k = 0; k < KNN; ++k) {
                    if (cd < bd[k]) {
                        float td = bd[k]; bd[k] = cd; cd = td;
                        int   ti = bi[k]; bi[k] = ci; ci = ti;
                    }
                }
            }
        }
        float fx = F[i*3+0], fy = F[i*3+1], fz = F[i*3+2];
        float s = 0.0f;
        #pragma unroll
        for (int k = 0; k < KNN; ++k) {
            int j = bi[k];
            float dx = fx - F[j*3+0];
            float dy = fy - F[j*3+1];
            float dz = fz - F[j*3+2];
            s += sqrtf(fmaf(dx, dx, fmaf(dy, dy, dz*dz)));
        }
        psum[p_local] = s;
    }
    __syncthreads();
    if (threadIdx.x == 0) {
        float t = 0.0f;
        #pragma unroll 8
        for (int k = 0; k < 32; ++k) t += psum[k];
        // W_SMOOTH / (B * N * K)
        atomicAdd(out, t * (0.5f / ((float)BATCH * N_PTS * KNN)));
    }
}

extern "C" void kernel_launch(void* const* d_in, const int* in_sizes, int n_in,
                              void* d_out, int out_size, void* d_ws, size_t ws_size,
                              hipStream_t stream) {
    const float* pc1  = (const float*)d_in[0];
    const float* pc2  = (const float*)d_in[1];
    const float* flow = (const float*)d_in[2];
    float* out = (float*)d_out;
    unsigned int* mins = (unsigned int*)d_ws;  // 2 * B*N uints = 128 KiB

    init_kernel<<<dim3(128), 256, 0, stream>>>(mins, out, 2 * BATCH * N_PTS);

    dim3 gch(N_PTS / 256, 16, BATCH);  // 32 row-tiles × 16 col-slices × 2
    chamfer_min_kernel<<<gch, 256, 0, stream>>>(pc1, pc2, flow, mins, 0);
    chamfer_min_kernel<<<gch, 256, 0, stream>>>(pc1, pc2, flow, mins + BATCH * N_PTS, 1);

    chamfer_reduce_kernel<<<dim3(2 * BATCH * N_PTS / 256), 256, 0, stream>>>(mins, out);

    smooth_kernel<<<dim3(N_PTS / 32, BATCH), 256, 0, stream>>>(pc1, flow, out);
}

// Round 2
// 201.387 us; speedup vs baseline: 2.9476x; 2.9476x over previous
//
#include <hip/hip_runtime.h>

#define N_PTS 8192
#define BATCH 2
#define KNN 8
#define STILE 2048     // smoothness LDS tile (points)
#define CH_R 4         // chamfer rows per thread
#define CH_SLICE 256   // chamfer candidates per block

// ---------------- init: min arrays to +inf bits, out to 0 ----------------
__global__ void init_kernel(unsigned int* __restrict__ mins, float* __restrict__ out, int n) {
    int i = blockIdx.x * blockDim.x + threadIdx.x;
    if (i < n) mins[i] = 0x7F800000u;  // +inf
    if (i == 0) out[0] = 0.0f;
}

// ---------------- chamfer directional min, 4 rows/thread ----------------
// dir==0: rows = pc1+flow, cols = pc2   (d1)
// dir==1: rows = pc2,      cols = pc1+flow (d2)
__global__ void chamfer_min_kernel(const float* __restrict__ pc1,
                                   const float* __restrict__ pc2,
                                   const float* __restrict__ flow,
                                   unsigned int* __restrict__ mins,
                                   int dir) {
    const int b = blockIdx.z;
    const int i0 = blockIdx.x * (256 * CH_R) + threadIdx.x * CH_R;
    const float* base1 = pc1 + (size_t)b * N_PTS * 3;
    const float* base2 = pc2 + (size_t)b * N_PTS * 3;
    const float* fl    = flow + (size_t)b * N_PTS * 3;

    float px[CH_R], py[CH_R], pz[CH_R];
    #pragma unroll
    for (int r = 0; r < CH_R; ++r) {
        int row = i0 + r;
        if (dir == 0) {
            px[r] = base1[row*3+0] + fl[row*3+0];
            py[r] = base1[row*3+1] + fl[row*3+1];
            pz[r] = base1[row*3+2] + fl[row*3+2];
        } else {
            px[r] = base2[row*3+0];
            py[r] = base2[row*3+1];
            pz[r] = base2[row*3+2];
        }
    }

    const int m0 = blockIdx.y * CH_SLICE;
    __shared__ float sm[CH_SLICE * 3];
    // stage 256 candidates = 768 floats = 192 float4
    if (threadIdx.x < CH_SLICE * 3 / 4) {
        float4 v;
        if (dir == 0) {
            v = ((const float4*)(base2 + (size_t)m0 * 3))[threadIdx.x];
        } else {
            float4 a = ((const float4*)(base1 + (size_t)m0 * 3))[threadIdx.x];
            float4 f = ((const float4*)(fl    + (size_t)m0 * 3))[threadIdx.x];
            v = make_float4(a.x + f.x, a.y + f.y, a.z + f.z, a.w + f.w);
        }
        ((float4*)sm)[threadIdx.x] = v;
    }
    __syncthreads();

    float best[CH_R];
    #pragma unroll
    for (int r = 0; r < CH_R; ++r) best[r] = __builtin_inff();

    #pragma unroll 8
    for (int jj = 0; jj < CH_SLICE; ++jj) {
        float ox = sm[jj*3+0], oy = sm[jj*3+1], oz = sm[jj*3+2];
        #pragma unroll
        for (int r = 0; r < CH_R; ++r) {
            float dx = px[r] - ox;
            float dy = py[r] - oy;
            float dz = pz[r] - oz;
            float d = fmaf(dx, dx, fmaf(dy, dy, dz*dz));
            best[r] = fminf(best[r], d);
        }
    }
    #pragma unroll
    for (int r = 0; r < CH_R; ++r)
        atomicMin(&mins[(size_t)b * N_PTS + i0 + r], __float_as_uint(best[r]));
}

// ---------------- chamfer reduce: sum sqrt(min)/(B*N) ----------------
__global__ void chamfer_reduce_kernel(const unsigned int* __restrict__ mins,
                                      float* __restrict__ out) {
    int i = blockIdx.x * 256 + threadIdx.x;  // 128 blocks * 256 = 32768 entries
    float v = sqrtf(__uint_as_float(mins[i])) * (1.0f / (float)(BATCH * N_PTS));
    #pragma unroll
    for (int off = 32; off > 0; off >>= 1) v += __shfl_down(v, off, 64);
    __shared__ float wsum[4];
    int wid = threadIdx.x >> 6;
    if ((threadIdx.x & 63) == 0) wsum[wid] = v;
    __syncthreads();
    if (threadIdx.x == 0) {
        atomicAdd(out, wsum[0] + wsum[1] + wsum[2] + wsum[3]);
    }
}

// ---------------- smoothness: kNN-8 via packed-key branchless insert ----------------
// 256 threads: 32 points/block, 8 sub-threads/point (interleaved j scan).
// key = (f32bits(d2) & 0xFFFFE000) | j  — monotone in truncated d2, ties by j.
__global__ void smooth_kernel(const float* __restrict__ pc1,
                              const float* __restrict__ flow,
                              float* __restrict__ out) {
    const int b = blockIdx.y;
    const int p_local = threadIdx.x >> 3;  // 0..31
    const int sub     = threadIdx.x & 7;   // 0..7
    const int i = blockIdx.x * 32 + p_local;
    const float* P = pc1  + (size_t)b * N_PTS * 3;
    const float* F = flow + (size_t)b * N_PTS * 3;

    const float px = P[i*3+0], py = P[i*3+1], pz = P[i*3+2];

    // sorted top-8 keys, o0 <= o1 <= ... <= o7, named scalars (registers)
    unsigned o0 = 0xFFFFFFFFu, o1 = 0xFFFFFFFFu, o2 = 0xFFFFFFFFu, o3 = 0xFFFFFFFFu;
    unsigned o4 = 0xFFFFFFFFu, o5 = 0xFFFFFFFFu, o6 = 0xFFFFFFFFu, o7 = 0xFFFFFFFFu;

    __shared__ float sj[STILE * 3];  // 24 KiB; reused for merge below

    for (int t0 = 0; t0 < N_PTS; t0 += STILE) {
        __syncthreads();
        const float4* src = (const float4*)(P + (size_t)t0 * 3);
        float4* dst = (float4*)sj;
        for (int u = threadIdx.x; u < STILE * 3 / 4; u += 256) dst[u] = src[u];
        __syncthreads();
        #pragma unroll 8
        for (int jj = sub; jj < STILE; jj += 8) {
            int j = t0 + jj;
            float dx = px - sj[jj*3+0];
            float dy = py - sj[jj*3+1];
            float dz = pz - sj[jj*3+2];
            float d = fmaf(dx, dx, fmaf(dy, dy, dz*dz));
            unsigned key = (__float_as_uint(d) & 0xFFFFE000u) | (unsigned)j;
            key = (j == i) ? 0xFFFFFFFFu : key;
            // branchless sorted insert: new_k = max(old_{k-1}, min(key, old_k))
            unsigned n0 = min(o0, key);
            unsigned n1 = max(o0, min(o1, key));
            unsigned n2 = max(o1, min(o2, key));
            unsigned n3 = max(o2, min(o3, key));
            unsigned n4 = max(o3, min(o4, key));
            unsigned n5 = max(o4, min(o5, key));
            unsigned n6 = max(o5, min(o6, key));
            unsigned n7 = max(o6, min(o7, key));
            o0=n0; o1=n1; o2=n2; o3=n3; o4=n4; o5=n5; o6=n6; o7=n7;
        }
    }

    // merge the 8 sub-threads' sorted lists per point via LDS
    __syncthreads();
    unsigned* km = (unsigned*)sj;  // [32][64]
    km[p_local*64 + sub*8 + 0] = o0;
    km[p_local*64 + sub*8 + 1] = o1;
    km[p_local*64 + sub*8 + 2] = o2;
    km[p_local*64 + sub*8 + 3] = o3;
    km[p_local*64 + sub*8 + 4] = o4;
    km[p_local*64 + sub*8 + 5] = o5;
    km[p_local*64 + sub*8 + 6] = o6;
    km[p_local*64 + sub*8 + 7] = o7;
    __syncthreads();

    __shared__ float psum[32];
    if (sub == 0) {
        // own 8 already in o0..o7; insert the other 56
        for (int c = 8; c < 64; ++c) {
            unsigned key = km[p_local*64 + c];
            unsigned n0 = min(o0, key);
            unsigned n1 = max(o0, min(o1, key));
            unsigned n2 = max(o1, min(o2, key));
            unsigned n3 = max(o2, min(o3, key));
            unsigned n4 = max(o3, min(o4, key));
            unsigned n5 = max(o4, min(o5, key));
            unsigned n6 = max(o5, min(o6, key));
            unsigned n7 = max(o6, min(o7, key));
            o0=n0; o1=n1; o2=n2; o3=n3; o4=n4; o5=n5; o6=n6; o7=n7;
        }
        float fx = F[i*3+0], fy = F[i*3+1], fz = F[i*3+2];
        float s = 0.0f;
        unsigned ks[KNN] = {o0,o1,o2,o3,o4,o5,o6,o7};
        #pragma unroll
        for (int k = 0; k < KNN; ++k) {
            int j = (int)(ks[k] & 0x1FFFu);
            float dx = fx - F[j*3+0];
            float dy = fy - F[j*3+1];
            float dz = fz - F[j*3+2];
            s += sqrtf(fmaf(dx, dx, fmaf(dy, dy, dz*dz)));
        }
        psum[p_local] = s;
    }
    __syncthreads();
    if (threadIdx.x == 0) {
        float t = 0.0f;
        #pragma unroll 8
        for (int k = 0; k < 32; ++k) t += psum[k];
        atomicAdd(out, t * (0.5f / ((float)BATCH * N_PTS * KNN)));
    }
}

extern "C" void kernel_launch(void* const* d_in, const int* in_sizes, int n_in,
                              void* d_out, int out_size, void* d_ws, size_t ws_size,
                              hipStream_t stream) {
    const float* pc1  = (const float*)d_in[0];
    const float* pc2  = (const float*)d_in[1];
    const float* flow = (const float*)d_in[2];
    float* out = (float*)d_out;
    unsigned int* mins = (unsigned int*)d_ws;  // 2 * B*N uints = 128 KiB

    init_kernel<<<dim3(128), 256, 0, stream>>>(mins, out, 2 * BATCH * N_PTS);

    dim3 gch(N_PTS / (256 * CH_R), N_PTS / CH_SLICE, BATCH);  // 8 x 32 x 2
    chamfer_min_kernel<<<gch, 256, 0, stream>>>(pc1, pc2, flow, mins, 0);
    chamfer_min_kernel<<<gch, 256, 0, stream>>>(pc1, pc2, flow, mins + BATCH * N_PTS, 1);

    chamfer_reduce_kernel<<<dim3(2 * BATCH * N_PTS / 256), 256, 0, stream>>>(mins, out);

    smooth_kernel<<<dim3(N_PTS / 32, BATCH), 256, 0, stream>>>(pc1, flow, out);
}

// Round 3
// 188.994 us; speedup vs baseline: 3.1409x; 1.0656x over previous
//
#include <hip/hip_runtime.h>

#define N_PTS 8192
#define BATCH 2
#define KNN 8
#define STILE 2048     // smoothness LDS tile (points), 32 KiB as float4
#define SUBS 16        // sub-threads per point
#define PPB 16         // points per block (256 threads)
#define CH_R 4         // chamfer rows per thread
#define CH_SLICE 256   // chamfer candidates per block

// ---------------- helpers ----------------
__device__ __forceinline__ void ce(unsigned &x, unsigned &y) {
    unsigned lo = min(x, y), hi = max(x, y); x = lo; y = hi;
}

// branchless sorted insert into ascending 8-list (15 min/max)
__device__ __forceinline__ void insert8(unsigned o[8], unsigned key) {
    unsigned n0 = min(o[0], key);
    unsigned n1 = max(o[0], min(o[1], key));
    unsigned n2 = max(o[1], min(o[2], key));
    unsigned n3 = max(o[2], min(o[3], key));
    unsigned n4 = max(o[3], min(o[4], key));
    unsigned n5 = max(o[4], min(o[5], key));
    unsigned n6 = max(o[5], min(o[6], key));
    unsigned n7 = max(o[6], min(o[7], key));
    o[0]=n0;o[1]=n1;o[2]=n2;o[3]=n3;o[4]=n4;o[5]=n5;o[6]=n6;o[7]=n7;
}

// butterfly merge stage: merge my sorted-8 with lane^d's sorted-8, keep lowest 8.
// c = min(a_i, b_{7-i}) is bitonic -> 12-CE cleanup sorts ascending.
__device__ __forceinline__ void merge_stage(unsigned o[8], int d) {
    unsigned p[8], c[8];
    #pragma unroll
    for (int k = 0; k < 8; ++k) p[k] = __shfl_xor(o[k], d, 64);
    #pragma unroll
    for (int k = 0; k < 8; ++k) c[k] = min(o[k], p[7-k]);
    ce(c[0],c[4]); ce(c[1],c[5]); ce(c[2],c[6]); ce(c[3],c[7]);
    ce(c[0],c[2]); ce(c[1],c[3]); ce(c[4],c[6]); ce(c[5],c[7]);
    ce(c[0],c[1]); ce(c[2],c[3]); ce(c[4],c[5]); ce(c[6],c[7]);
    #pragma unroll
    for (int k = 0; k < 8; ++k) o[k] = c[k];
}

// ---------------- init: min arrays to +inf bits, out to 0 ----------------
__global__ void init_kernel(unsigned int* __restrict__ mins, float* __restrict__ out, int n) {
    int i = blockIdx.x * blockDim.x + threadIdx.x;
    if (i < n) mins[i] = 0x7F800000u;  // +inf
    if (i == 0) out[0] = 0.0f;
}

// ---------------- chamfer: both directions in one launch ----------------
// blockIdx.z: bit0 = batch, bit1 = dir. dir0: rows=pc1+flow scan pc2; dir1: rows=pc2 scan pc1+flow.
__global__ __launch_bounds__(256) void chamfer_min_kernel(const float* __restrict__ pc1,
                                                          const float* __restrict__ pc2,
                                                          const float* __restrict__ flow,
                                                          unsigned* __restrict__ mins) {
    const int z = blockIdx.z;
    const int b = z & 1, dir = z >> 1;
    const int tid = threadIdx.x;
    const float* base1 = pc1 + (size_t)b * N_PTS * 3;
    const float* base2 = pc2 + (size_t)b * N_PTS * 3;
    const float* fl    = flow + (size_t)b * N_PTS * 3;

    __shared__ float  sraw[CH_SLICE * 3];  // 3 KiB
    __shared__ float4 sq[CH_SLICE];        // 4 KiB: (qx,qy,qz,|q|^2)
    const int m0 = blockIdx.y * CH_SLICE;

    if (tid < CH_SLICE * 3 / 4) {
        float4 v;
        if (dir == 0) {
            v = ((const float4*)(base2 + (size_t)m0 * 3))[tid];
        } else {
            float4 a = ((const float4*)(base1 + (size_t)m0 * 3))[tid];
            float4 f = ((const float4*)(fl    + (size_t)m0 * 3))[tid];
            v = make_float4(a.x + f.x, a.y + f.y, a.z + f.z, a.w + f.w);
        }
        ((float4*)sraw)[tid] = v;
    }

    const int i0 = blockIdx.x * (256 * CH_R) + tid * CH_R;
    float mx[CH_R], my_[CH_R], mz_[CH_R], p2[CH_R], best[CH_R];
    #pragma unroll
    for (int r = 0; r < CH_R; ++r) {
        int row = i0 + r;
        float px, py, pz;
        if (dir == 0) {
            px = base1[row*3+0] + fl[row*3+0];
            py = base1[row*3+1] + fl[row*3+1];
            pz = base1[row*3+2] + fl[row*3+2];
        } else {
            px = base2[row*3+0]; py = base2[row*3+1]; pz = base2[row*3+2];
        }
        mx[r] = -2.0f * px; my_[r] = -2.0f * py; mz_[r] = -2.0f * pz;
        p2[r] = fmaf(px, px, fmaf(py, py, pz * pz));
        best[r] = __builtin_inff();
    }
    __syncthreads();
    {
        float qx = sraw[tid*3+0], qy = sraw[tid*3+1], qz = sraw[tid*3+2];
        sq[tid] = make_float4(qx, qy, qz, fmaf(qx, qx, fmaf(qy, qy, qz * qz)));
    }
    __syncthreads();

    #pragma unroll 4
    for (int jj = 0; jj < CH_SLICE; ++jj) {
        float4 q = sq[jj];
        #pragma unroll
        for (int r = 0; r < CH_R; ++r) {
            // s = |q|^2 - 2 p.q ; d2 = s + |p|^2 (folded out of the loop)
            float s = fmaf(mx[r], q.x, fmaf(my_[r], q.y, fmaf(mz_[r], q.z, q.w)));
            best[r] = fminf(best[r], s);
        }
    }
    #pragma unroll
    for (int r = 0; r < CH_R; ++r) {
        float d2 = fmaxf(best[r] + p2[r], 0.0f);
        atomicMin(&mins[((size_t)dir * BATCH + b) * N_PTS + i0 + r], __float_as_uint(d2));
    }
}

// ---------------- chamfer reduce: sum sqrt(min)/(B*N) ----------------
__global__ void chamfer_reduce_kernel(const unsigned int* __restrict__ mins,
                                      float* __restrict__ out) {
    int i = blockIdx.x * 256 + threadIdx.x;  // 128 blocks * 256 = 32768 entries
    float v = sqrtf(__uint_as_float(mins[i])) * (1.0f / (float)(BATCH * N_PTS));
    #pragma unroll
    for (int off = 32; off > 0; off >>= 1) v += __shfl_down(v, off, 64);
    __shared__ float wsum[4];
    int wid = threadIdx.x >> 6;
    if ((threadIdx.x & 63) == 0) wsum[wid] = v;
    __syncthreads();
    if (threadIdx.x == 0) {
        atomicAdd(out, wsum[0] + wsum[1] + wsum[2] + wsum[3]);
    }
}

// ---------------- smoothness: kNN-8, threshold-gated insert ----------------
// 256 threads = 16 points x 16 subs. Tile 0 = sample pass (full insert) ->
// per-point threshold via butterfly merge; tiles 1..3 gated on __any(key<=thr).
__global__ __launch_bounds__(256) void smooth_kernel(const float* __restrict__ pc1,
                                                     const float* __restrict__ flow,
                                                     float* __restrict__ out) {
    const int b = blockIdx.y;
    const int tid = threadIdx.x;
    const int sub = tid & (SUBS - 1);
    const int p_local = tid >> 4;
    const int base_i = blockIdx.x * PPB;
    const int i = base_i + p_local;
    const float* P = pc1  + (size_t)b * N_PTS * 3;
    const float* F = flow + (size_t)b * N_PTS * 3;

    const float px = P[i*3+0], py = P[i*3+1], pz = P[i*3+2];
    const float mx = -2.0f * px, my = -2.0f * py, mz = -2.0f * pz;
    const float p2 = fmaf(px, px, fmaf(py, py, pz * pz));

    unsigned o[8];
    #pragma unroll
    for (int k = 0; k < 8; ++k) o[k] = 0xFFFFFFFFu;
    unsigned thr = 0xFFFFFFFFu;

    __shared__ float4 sq[STILE];  // 32 KiB: (qx,qy,qz,|q|^2)

    for (int t0 = 0; t0 < N_PTS; t0 += STILE) {
        __syncthreads();
        for (int u = tid; u < STILE; u += 256) {
            int g = t0 + u;
            float qx = P[g*3+0], qy = P[g*3+1], qz = P[g*3+2];
            sq[u] = make_float4(qx, qy, qz, fmaf(qx, qx, fmaf(qy, qy, qz * qz)));
        }
        __syncthreads();
        const bool self_here = ((base_i & ~(STILE - 1)) == t0);  // block-uniform
        if (t0 == 0) {
            // Phase A: sample pass, unconditional insert
            #pragma unroll 4
            for (int jj = sub; jj < STILE; jj += SUBS) {
                float4 q = sq[jj];
                float d2 = fmaxf(fmaf(mx, q.x, fmaf(my, q.y, fmaf(mz, q.z, q.w))) + p2, 0.0f);
                unsigned key = (__float_as_uint(d2) & 0xFFFFE000u) | (unsigned)jj;
                if (self_here && jj == i) key = 0xFFFFFFFFu;
                insert8(o, key);
            }
            unsigned m[8];
            #pragma unroll
            for (int k = 0; k < 8; ++k) m[k] = o[k];
            merge_stage(m, 1); merge_stage(m, 2); merge_stage(m, 4); merge_stage(m, 8);
            thr = m[7];  // >= true 8th-NN key (sample subset)
        } else {
            // Phase B: gated insert
            #pragma unroll 4
            for (int jj = sub; jj < STILE; jj += SUBS) {
                float4 q = sq[jj];
                float d2 = fmaxf(fmaf(mx, q.x, fmaf(my, q.y, fmaf(mz, q.z, q.w))) + p2, 0.0f);
                int j = t0 + jj;
                unsigned key = (__float_as_uint(d2) & 0xFFFFE000u) | (unsigned)j;
                if (self_here && j == i) key = 0xFFFFFFFFu;
                if (__any(key <= thr)) insert8(o, key);
            }
        }
    }

    // final butterfly: all 16 lanes of a point end with identical sorted top-8
    merge_stage(o, 1); merge_stage(o, 2); merge_stage(o, 4); merge_stage(o, 8);

    // lane handles neighbor (sub & 7); each neighbor counted twice -> x0.5 in scale
    const int k = sub & 7;
    unsigned key = o[0];
    #pragma unroll
    for (int kk = 1; kk < 8; ++kk) key = (k == kk) ? o[kk] : key;
    int j = (int)(key & (N_PTS - 1));
    float fx = F[i*3+0], fy = F[i*3+1], fz = F[i*3+2];
    float dx = fx - F[j*3+0], dy = fy - F[j*3+1], dz = fz - F[j*3+2];
    float s = sqrtf(fmaf(dx, dx, fmaf(dy, dy, dz * dz)));
    #pragma unroll
    for (int d = 1; d < 64; d <<= 1) s += __shfl_xor(s, d, 64);
    if ((tid & 63) == 0) {
        // W_SMOOTH(0.5) * 0.5(double count) / (B*N*K)
        atomicAdd(out, s * (0.25f / ((float)BATCH * N_PTS * KNN)));
    }
}

extern "C" void kernel_launch(void* const* d_in, const int* in_sizes, int n_in,
                              void* d_out, int out_size, void* d_ws, size_t ws_size,
                              hipStream_t stream) {
    const float* pc1  = (const float*)d_in[0];
    const float* pc2  = (const float*)d_in[1];
    const float* flow = (const float*)d_in[2];
    float* out = (float*)d_out;
    unsigned int* mins = (unsigned int*)d_ws;  // 2*B*N uints = 128 KiB

    init_kernel<<<dim3(128), 256, 0, stream>>>(mins, out, 2 * BATCH * N_PTS);

    dim3 gch(N_PTS / (256 * CH_R), N_PTS / CH_SLICE, 2 * BATCH);  // 8 x 32 x 4
    chamfer_min_kernel<<<gch, 256, 0, stream>>>(pc1, pc2, flow, mins);

    chamfer_reduce_kernel<<<dim3(2 * BATCH * N_PTS / 256), 256, 0, stream>>>(mins, out);

    smooth_kernel<<<dim3(N_PTS / PPB, BATCH), 256, 0, stream>>>(pc1, flow, out);
}